// Round 1
// baseline (772.128 us; speedup 1.0000x reference)
//
#include <hip/hip_runtime.h>
#include <hip/hip_bf16.h>

using bf16x8 = __attribute__((ext_vector_type(8))) short;
using f32x4  = __attribute__((ext_vector_type(4))) float;
using u16x4  = __attribute__((ext_vector_type(4))) unsigned short;

constexpr int Ht = 60, Wt = 108, NHEAD = 4, C = 512;
constexpr int GWt = 14, NWIN = 112, NTOK = Ht * Wt, BT = 16;
constexpr float SCALE = 0.08838834764831845f;   // 1/sqrt(128)

// LDS layout (bytes). All tiles XOR-swizzled: byte ^= (row&7)<<4
constexpr int O_XW = 0;            // [64][512] bf16   window tokens      65536
constexpr int O_AB = 65536;        // 4 x [64][128] bf16 (Q, then attn)   65536
constexpr int O_KV = 131072;       // [64][128] K  /  [128][64] Vt        16384
constexpr int O_P  = 147456;       // [64][64] bf16 P                      8192
constexpr int LDS_BYTES = 155648;

__device__ __forceinline__ unsigned short f2b(float f) {   // f32 -> bf16 RNE
  union { float f; unsigned u; } v; v.f = f;
  unsigned r = v.u + 0x7fffu + ((v.u >> 16) & 1u);
  return (unsigned short)(r >> 16);
}

__global__ void cvt_weights(const float* __restrict__ a, const float* __restrict__ b,
                            const float* __restrict__ c, const float* __restrict__ d,
                            unsigned short* __restrict__ dst) {
  int i = blockIdx.x * blockDim.x + threadIdx.x;   // 262144 threads, 4 f32 each
  int m  = i >> 16;
  int o4 = i & 65535;
  const float* src = (m == 0) ? a : (m == 1) ? b : (m == 2) ? c : d;
  float4 v = *(const float4*)(src + (size_t)o4 * 4);
  u16x4 o;
  o[0] = f2b(v.x); o[1] = f2b(v.y); o[2] = f2b(v.z); o[3] = f2b(v.w);
  *(u16x4*)(dst + (size_t)m * 262144 + (size_t)o4 * 4) = o;
}

extern "C" __global__ __launch_bounds__(256, 1)
void swmhsa_main(const float* __restrict__ x,
                 const unsigned short* __restrict__ wqkvo,   // [4][512][512] bf16
                 const float* __restrict__ bq, const float* __restrict__ bk,
                 const float* __restrict__ bv, const float* __restrict__ bo,
                 float* __restrict__ out)
{
  extern __shared__ char smem[];
  const int tid   = threadIdx.x;
  const int wvid  = tid >> 6;          // wave 0..3
  const int lane  = tid & 63;
  const int l15   = lane & 15;
  const int kl    = (lane >> 4) << 3;  // per-lane k offset in fragments
  const int rbase = (lane >> 4) << 2;  // acc row base

  const int blk = blockIdx.x;
  const int b   = blk / NWIN;
  const int w   = blk - b * NWIN;
  const int wy  = w / GWt, wx = w - wy * GWt;

  // ---- stage window tokens: f32 -> bf16, swizzled. Padded tokens = 0 ----
  for (int it = 0; it < 32; ++it) {
    int f  = it * 256 + tid;           // float4 index, 128 per row
    int r  = f >> 7;
    int c4 = f & 127;
    int gy = wy * 8 + (r >> 3), gx = wx * 8 + (r & 7);
    float4 v = make_float4(0.f, 0.f, 0.f, 0.f);
    if (gy < Ht && gx < Wt)
      v = *(const float4*)(x + ((size_t)b * NTOK + gy * Wt + gx) * C + c4 * 4);
    u16x4 o;
    o[0] = f2b(v.x); o[1] = f2b(v.y); o[2] = f2b(v.z); o[3] = f2b(v.w);
    int off = (r << 10) + (c4 << 3);
    off ^= (r & 7) << 4;
    *(u16x4*)(smem + O_XW + off) = o;
  }
  __syncthreads();

  // GEMM: out[64 x 32cols-per-wave] = xw(64x512) @ Wm_h^T ; both frags row-major-K
  auto gemm_qkv = [&](const unsigned short* wm, int h, f32x4 (&acc)[4][2]) {
    #pragma unroll
    for (int mt = 0; mt < 4; ++mt)
      #pragma unroll
      for (int nt = 0; nt < 2; ++nt) acc[mt][nt] = (f32x4){0.f, 0.f, 0.f, 0.f};
    for (int kk = 0; kk < 512; kk += 32) {
      int ka = kk + kl;
      bf16x8 afr[4];
      #pragma unroll
      for (int mt = 0; mt < 4; ++mt) {
        int row = mt * 16 + l15;
        int off = (row << 10) + (ka << 1);
        off ^= (row & 7) << 4;
        afr[mt] = *(const bf16x8*)(smem + O_XW + off);
      }
      bf16x8 bfr[2];
      #pragma unroll
      for (int nt = 0; nt < 2; ++nt) {
        int jg = h * 128 + wvid * 32 + nt * 16 + l15;
        bfr[nt] = *(const bf16x8*)(wm + (size_t)jg * 512 + ka);
      }
      #pragma unroll
      for (int mt = 0; mt < 4; ++mt)
        #pragma unroll
        for (int nt = 0; nt < 2; ++nt)
          acc[mt][nt] = __builtin_amdgcn_mfma_f32_16x16x32_bf16(afr[mt], bfr[nt], acc[mt][nt], 0, 0, 0);
    }
  };

  // store acc (row=token, col=feature) row-major [64][128] bf16 + bias, swizzled
  auto store_rm = [&](f32x4 (&acc)[4][2], char* base, const float* bias, int h) {
    #pragma unroll
    for (int nt = 0; nt < 2; ++nt) {
      int col = wvid * 32 + nt * 16 + l15;
      float bi = bias[h * 128 + col];
      #pragma unroll
      for (int mt = 0; mt < 4; ++mt)
        #pragma unroll
        for (int rg = 0; rg < 4; ++rg) {
          int row = mt * 16 + rbase + rg;
          int off = (row << 8) + (col << 1);
          off ^= (row & 7) << 4;
          *(unsigned short*)(base + off) = f2b(acc[mt][nt][rg] + bi);
        }
    }
  };

  for (int h = 0; h < NHEAD; ++h) {
    char* ab = smem + O_AB + h * 16384;    // Q buffer, later attn_h buffer
    {
      f32x4 acc[4][2];
      gemm_qkv(wqkvo + 1 * 262144, h, acc);      // K
      store_rm(acc, smem + O_KV, bk, h);
      gemm_qkv(wqkvo + 0 * 262144, h, acc);      // Q
      store_rm(acc, ab, bq, h);
    }
    __syncthreads();
    {
      // scores: rows wvid*16..+15, all 64 keys, K=128
      f32x4 sacc[4];
      #pragma unroll
      for (int nt = 0; nt < 4; ++nt) sacc[nt] = (f32x4){0.f, 0.f, 0.f, 0.f};
      for (int kk = 0; kk < 128; kk += 32) {
        int ka = kk + kl;
        int row = wvid * 16 + l15;
        int off = (row << 8) + (ka << 1); off ^= (row & 7) << 4;
        bf16x8 afr = *(const bf16x8*)(ab + off);
        #pragma unroll
        for (int nt = 0; nt < 4; ++nt) {
          int jr = nt * 16 + l15;
          int o2 = (jr << 8) + (ka << 1); o2 ^= (jr & 7) << 4;
          bf16x8 bfr = *(const bf16x8*)(smem + O_KV + o2);
          sacc[nt] = __builtin_amdgcn_mfma_f32_16x16x32_bf16(afr, bfr, sacc[nt], 0, 0, 0);
        }
      }
      // softmax: row i = wvid*16 + (lane>>4)*4 + rg lives in one 16-lane group
      #pragma unroll
      for (int rg = 0; rg < 4; ++rg) {
        float m = -3.0e38f;
        #pragma unroll
        for (int nt = 0; nt < 4; ++nt) m = fmaxf(m, sacc[nt][rg]);
        #pragma unroll
        for (int dd = 1; dd < 16; dd <<= 1) m = fmaxf(m, __shfl_xor(m, dd, 64));
        float s = 0.f, e[4];
        #pragma unroll
        for (int nt = 0; nt < 4; ++nt) { e[nt] = __expf((sacc[nt][rg] - m) * SCALE); s += e[nt]; }
        #pragma unroll
        for (int dd = 1; dd < 16; dd <<= 1) s += __shfl_xor(s, dd, 64);
        float inv = 1.f / s;
        int row = wvid * 16 + rbase + rg;
        #pragma unroll
        for (int nt = 0; nt < 4; ++nt) {
          int col = nt * 16 + l15;
          int off = (row << 7) + (col << 1); off ^= (row & 7) << 4;
          *(unsigned short*)(smem + O_P + off) = f2b(e[nt] * inv);
        }
      }
    }
    __syncthreads();
    {
      f32x4 acc[4][2];
      gemm_qkv(wqkvo + 2 * 262144, h, acc);      // V, store transposed Vt[d][j]
      #pragma unroll
      for (int nt = 0; nt < 2; ++nt) {
        int d = wvid * 32 + nt * 16 + l15;
        float bi = bv[h * 128 + d];
        #pragma unroll
        for (int mt = 0; mt < 4; ++mt) {
          int j0 = mt * 16 + rbase;            // 4 consecutive tokens
          u16x4 pk;
          #pragma unroll
          for (int rg = 0; rg < 4; ++rg) pk[rg] = f2b(acc[mt][nt][rg] + bi);
          int off = (d << 7) + (j0 << 1); off ^= (d & 7) << 4;
          *(u16x4*)(smem + O_KV + off) = pk;
        }
      }
    }
    __syncthreads();
    {
      // attn_h = P @ V : M=64, N=128 (wave owns 32), K=64
      f32x4 pacc[4][2];
      #pragma unroll
      for (int mt = 0; mt < 4; ++mt)
        #pragma unroll
        for (int nt = 0; nt < 2; ++nt) pacc[mt][nt] = (f32x4){0.f, 0.f, 0.f, 0.f};
      #pragma unroll
      for (int kk = 0; kk < 64; kk += 32) {
        int ka = kk + kl;
        bf16x8 afr[4];
        #pragma unroll
        for (int mt = 0; mt < 4; ++mt) {
          int row = mt * 16 + l15;
          int off = (row << 7) + (ka << 1); off ^= (row & 7) << 4;
          afr[mt] = *(const bf16x8*)(smem + O_P + off);
        }
        bf16x8 bfr[2];
        #pragma unroll
        for (int nt = 0; nt < 2; ++nt) {
          int d = wvid * 32 + nt * 16 + l15;
          int off = (d << 7) + (ka << 1); off ^= (d & 7) << 4;
          bfr[nt] = *(const bf16x8*)(smem + O_KV + off);
        }
        #pragma unroll
        for (int mt = 0; mt < 4; ++mt)
          #pragma unroll
          for (int nt = 0; nt < 2; ++nt)
            pacc[mt][nt] = __builtin_amdgcn_mfma_f32_16x16x32_bf16(afr[mt], bfr[nt], pacc[mt][nt], 0, 0, 0);
      }
      #pragma unroll
      for (int nt = 0; nt < 2; ++nt) {
        int d = wvid * 32 + nt * 16 + l15;
        #pragma unroll
        for (int mt = 0; mt < 4; ++mt)
          #pragma unroll
          for (int rg = 0; rg < 4; ++rg) {
            int row = mt * 16 + rbase + rg;
            int off = (row << 8) + (d << 1); off ^= (row & 7) << 4;
            *(unsigned short*)(ab + off) = f2b(pacc[mt][nt][rg]);
          }
      }
    }
    __syncthreads();
  }

  // ---- output projection: y = attn(64x512) @ Wo^T + bo, scatter valid tokens ----
  const unsigned short* wo = wqkvo + 3 * 262144;
  for (int half = 0; half < 2; ++half) {
    f32x4 oacc[4][4];
    #pragma unroll
    for (int mt = 0; mt < 4; ++mt)
      #pragma unroll
      for (int nt = 0; nt < 4; ++nt) oacc[mt][nt] = (f32x4){0.f, 0.f, 0.f, 0.f};
    for (int kk = 0; kk < 512; kk += 32) {
      const char* abk = smem + O_AB + (kk >> 7) * 16384;   // head = kk/128
      int ka = (kk & 127) + kl;
      bf16x8 afr[4];
      #pragma unroll
      for (int mt = 0; mt < 4; ++mt) {
        int row = mt * 16 + l15;
        int off = (row << 8) + (ka << 1); off ^= (row & 7) << 4;
        afr[mt] = *(const bf16x8*)(abk + off);
      }
      bf16x8 bfr[4];
      #pragma unroll
      for (int nt = 0; nt < 4; ++nt) {
        int j = wvid * 128 + half * 64 + nt * 16 + l15;
        bfr[nt] = *(const bf16x8*)(wo + (size_t)j * 512 + kk + kl);
      }
      #pragma unroll
      for (int mt = 0; mt < 4; ++mt)
        #pragma unroll
        for (int nt = 0; nt < 4; ++nt)
          oacc[mt][nt] = __builtin_amdgcn_mfma_f32_16x16x32_bf16(afr[mt], bfr[nt], oacc[mt][nt], 0, 0, 0);
    }
    #pragma unroll
    for (int mt = 0; mt < 4; ++mt) {
      #pragma unroll
      for (int rg = 0; rg < 4; ++rg) {
        int r = mt * 16 + rbase + rg;
        int gy = wy * 8 + (r >> 3), gx = wx * 8 + (r & 7);
        if (gy < Ht && gx < Wt) {
          float* po = out + ((size_t)b * NTOK + gy * Wt + gx) * C;
          #pragma unroll
          for (int nt = 0; nt < 4; ++nt) {
            int j = wvid * 128 + half * 64 + nt * 16 + l15;
            po[j] = oacc[mt][nt][rg] + bo[j];
          }
        }
      }
    }
  }
}

extern "C" void kernel_launch(void* const* d_in, const int* in_sizes, int n_in,
                              void* d_out, int out_size, void* d_ws, size_t ws_size,
                              hipStream_t stream) {
  const float* x  = (const float*)d_in[0];
  // d_in[1] = t (unused by reference)
  const float* Wq = (const float*)d_in[2];
  const float* bq = (const float*)d_in[3];
  const float* Wk = (const float*)d_in[4];
  const float* bk = (const float*)d_in[5];
  const float* Wv = (const float*)d_in[6];
  const float* bv = (const float*)d_in[7];
  const float* Wo = (const float*)d_in[8];
  const float* bo = (const float*)d_in[9];
  unsigned short* wbf = (unsigned short*)d_ws;   // 4 x 512 x 512 bf16 = 2 MB

  cvt_weights<<<1024, 256, 0, stream>>>(Wq, Wk, Wv, Wo, wbf);

  hipFuncSetAttribute((const void*)swmhsa_main,
                      hipFuncAttributeMaxDynamicSharedMemorySize, LDS_BYTES);
  swmhsa_main<<<BT * NWIN, 256, LDS_BYTES, stream>>>(
      x, wbf, bq, bk, bv, bo, (float*)d_out);
}